// Round 1
// baseline (440.323 us; speedup 1.0000x reference)
//
#include <hip/hip_runtime.h>
#include <hip/hip_bf16.h>
#include <stdint.h>

typedef __attribute__((ext_vector_type(8))) short short8;
typedef __attribute__((ext_vector_type(4))) float f32x4;

#define M_DIM 8192
#define N_DIM 4096
#define K_DIM 4096
#define BM 128
#define BN 128
#define BK 64

static __device__ __forceinline__ unsigned short f32_to_bf16(float f) {
  union { float f; unsigned int u; } v; v.f = f;
  unsigned int u = v.u;
  u += 0x7fffu + ((u >> 16) & 1u);   // round-to-nearest-even
  return (unsigned short)(u >> 16);
}

// ---------------- cast x (f32 -> bf16), 8 elems/thread ----------------
__global__ void cast_x_kernel(const float* __restrict__ x,
                              unsigned short* __restrict__ xb) {
  size_t i = ((size_t)blockIdx.x * blockDim.x + threadIdx.x) * 8;
  if (i >= (size_t)M_DIM * K_DIM) return;
  float4 v0 = *reinterpret_cast<const float4*>(x + i);
  float4 v1 = *reinterpret_cast<const float4*>(x + i + 4);
  short8 o;
  o[0] = (short)f32_to_bf16(v0.x);
  o[1] = (short)f32_to_bf16(v0.y);
  o[2] = (short)f32_to_bf16(v0.z);
  o[3] = (short)f32_to_bf16(v0.w);
  o[4] = (short)f32_to_bf16(v1.x);
  o[5] = (short)f32_to_bf16(v1.y);
  o[6] = (short)f32_to_bf16(v1.z);
  o[7] = (short)f32_to_bf16(v1.w);
  *reinterpret_cast<short8*>(xb + i) = o;
}

// ---------------- dequant: bit-planes -> bf16 W[N][K] ----------------
// Mapping derived from reference:
//   feature i -> chunk c = (i>>10)*32 + ((i>>3)&31), byte r = ((i>>8)&3)^3,
//   bit (7 - (i&7)); weight code = sum_k bit_k << (7-k) over the 8 planes.
// Inverse, per (n, c): wp=c>>5, t=c&31; features i = wp*1024 + s*256 + t*8 + u,
//   s in 0..3 (byte r = s^3), u in 0..7.
__global__ void dequant_kernel(const int* __restrict__ qw,
                               const float* __restrict__ scale,
                               const float* __restrict__ zero,
                               unsigned short* __restrict__ W) {
  int idx = blockIdx.x * blockDim.x + threadIdx.x;   // n*128 + c
  if (idx >= N_DIM * 128) return;
  int n = idx >> 7;
  int c = idx & 127;
  unsigned int w[8];
#pragma unroll
  for (int k = 0; k < 8; ++k)
    w[k] = (unsigned int)qw[(size_t)k * (N_DIM * 128) + idx];
  int wp = c >> 5, t = c & 31;
#pragma unroll
  for (int s = 0; s < 4; ++s) {
    int r = s ^ 3;
    unsigned int by[8];
#pragma unroll
    for (int k = 0; k < 8; ++k) by[k] = (w[k] >> (8 * r)) & 0xffu;
    int ibase = wp * 1024 + s * 256 + t * 8;
    int g = ibase >> 7;                       // 128-feature group
    float sc = scale[n * 32 + g];
    float zp = zero[n * 32 + g] * 16.0f;      // zero * 2^(W_BITS-MIN_PREC)
    short8 o;
#pragma unroll
    for (int u = 0; u < 8; ++u) {
      unsigned int q = 0;
#pragma unroll
      for (int k = 0; k < 8; ++k)
        q |= ((by[k] >> (7 - u)) & 1u) << (7 - k);
      o[u] = (short)f32_to_bf16(sc * ((float)q - zp));
    }
    *reinterpret_cast<short8*>(&W[(size_t)n * K_DIM + ibase]) = o;
  }
}

// ---------------- bf16 GEMM: C[M][N] = A[M][K] * B[N][K]^T + bias ----------------
// m97 structure: 128x128 tile, BK=64, 4 waves (2x2), 4x4 16x16x32 frags/wave,
// global_load_lds width-16 staging, 2 barriers per K-step.
__global__ __launch_bounds__(256) void gemm_kernel(
    const unsigned short* __restrict__ A,   // Xb [M][K] bf16
    const unsigned short* __restrict__ B,   // Wb [N][K] bf16
    const float* __restrict__ bias,
    float* __restrict__ C) {
  __shared__ unsigned short As[BM * BK];    // row-major [128][64], 16 KB
  __shared__ unsigned short Bs[BN * BK];

  int bid = blockIdx.x;
  // XCD-aware bijective swizzle (2048 % 8 == 0)
  int cpx = gridDim.x >> 3;
  int swz = (bid & 7) * cpx + (bid >> 3);
  int tm = swz >> 5;            // 64 M-tiles
  int tn = swz & 31;            // 32 N-tiles
  int m0 = tm * BM, n0 = tn * BN;

  int tid = threadIdx.x;
  int wid = tid >> 6, lane = tid & 63;
  int wr = wid >> 1, wc = wid & 1;

  f32x4 acc[4][4];
#pragma unroll
  for (int i = 0; i < 4; ++i)
#pragma unroll
    for (int j = 0; j < 4; ++j) acc[i][j] = (f32x4){0.f, 0.f, 0.f, 0.f};

  const int srow_sub = lane >> 3;       // 0..7 within a 1KB chunk
  const int scol = (lane & 7) * 8;      // bf16 col for staging

  for (int kt = 0; kt < K_DIM / BK; ++kt) {
    int k0 = kt * BK;
#pragma unroll
    for (int p = 0; p < 4; ++p) {
      int ci = wid * 4 + p;             // 16 chunks of 1 KB per tile
      int row = ci * 8 + srow_sub;
      const unsigned short* ga = A + (size_t)(m0 + row) * K_DIM + k0 + scol;
      __builtin_amdgcn_global_load_lds(
          (const __attribute__((address_space(1))) void*)ga,
          (__attribute__((address_space(3))) void*)&As[ci * 512], 16, 0, 0);
      const unsigned short* gb = B + (size_t)(n0 + row) * K_DIM + k0 + scol;
      __builtin_amdgcn_global_load_lds(
          (const __attribute__((address_space(1))) void*)gb,
          (__attribute__((address_space(3))) void*)&Bs[ci * 512], 16, 0, 0);
    }
    __syncthreads();                    // drains vmcnt before barrier

#pragma unroll
    for (int kk = 0; kk < 2; ++kk) {
      short8 a[4], b[4];
      int kb = kk * 32 + (lane >> 4) * 8;
#pragma unroll
      for (int mf = 0; mf < 4; ++mf) {
        int row = wr * 64 + mf * 16 + (lane & 15);
        a[mf] = *reinterpret_cast<const short8*>(&As[row * BK + kb]);
      }
#pragma unroll
      for (int nf = 0; nf < 4; ++nf) {
        int row = wc * 64 + nf * 16 + (lane & 15);
        b[nf] = *reinterpret_cast<const short8*>(&Bs[row * BK + kb]);
      }
#pragma unroll
      for (int mf = 0; mf < 4; ++mf)
#pragma unroll
        for (int nf = 0; nf < 4; ++nf)
          acc[mf][nf] = __builtin_amdgcn_mfma_f32_16x16x32_bf16(
              a[mf], b[nf], acc[mf][nf], 0, 0, 0);
    }
    __syncthreads();
  }

  // epilogue: C/D layout col=lane&15, row=(lane>>4)*4+j  [m89-verified]
#pragma unroll
  for (int nf = 0; nf < 4; ++nf) {
    int gcol = n0 + wc * 64 + nf * 16 + (lane & 15);
    float bv = bias[gcol];
#pragma unroll
    for (int mf = 0; mf < 4; ++mf) {
      int grow = m0 + wr * 64 + mf * 16 + ((lane >> 4) << 2);
      f32x4 v = acc[mf][nf];
#pragma unroll
      for (int j = 0; j < 4; ++j)
        C[(size_t)(grow + j) * N_DIM + gcol] = v[j] + bv;
    }
  }
}

extern "C" void kernel_launch(void* const* d_in, const int* in_sizes, int n_in,
                              void* d_out, int out_size, void* d_ws, size_t ws_size,
                              hipStream_t stream) {
  const float* x       = (const float*)d_in[0];
  const int*   qweight = (const int*)d_in[1];
  const float* scale   = (const float*)d_in[2];
  const float* zero    = (const float*)d_in[3];
  const float* bias    = (const float*)d_in[4];
  float* out = (float*)d_out;

  unsigned short* Xb = (unsigned short*)d_ws;                    // 64 MB
  unsigned short* Wb = Xb + (size_t)M_DIM * K_DIM;               // 32 MB

  cast_x_kernel<<<(M_DIM * K_DIM / 8) / 256, 256, 0, stream>>>(x, Xb);
  dequant_kernel<<<(N_DIM * 128) / 256, 256, 0, stream>>>(qweight, scale, zero, Wb);
  gemm_kernel<<<(M_DIM / BM) * (N_DIM / BN), 256, 0, stream>>>(Xb, Wb, bias, out);
}

// Round 2
// 301.113 us; speedup vs baseline: 1.4623x; 1.4623x over previous
//
#include <hip/hip_runtime.h>
#include <hip/hip_bf16.h>
#include <stdint.h>

typedef __attribute__((ext_vector_type(8))) short short8;
typedef __attribute__((ext_vector_type(4))) float f32x4;

#define M_DIM 8192
#define N_DIM 4096
#define K_DIM 4096
#define BM 256
#define BN 256
#define BK 64
#define NT (K_DIM / BK)   // 64 K-tiles, 32 iterations of 2

static __device__ __forceinline__ unsigned short f32_to_bf16(float f) {
  union { float f; unsigned int u; } v; v.f = f;
  unsigned int u = v.u;
  u += 0x7fffu + ((u >> 16) & 1u);   // round-to-nearest-even
  return (unsigned short)(u >> 16);
}

// ---------------- cast x (f32 -> bf16), 8 elems/thread ----------------
__global__ void cast_x_kernel(const float* __restrict__ x,
                              unsigned short* __restrict__ xb) {
  size_t i = ((size_t)blockIdx.x * blockDim.x + threadIdx.x) * 8;
  if (i >= (size_t)M_DIM * K_DIM) return;
  float4 v0 = *reinterpret_cast<const float4*>(x + i);
  float4 v1 = *reinterpret_cast<const float4*>(x + i + 4);
  short8 o;
  o[0] = (short)f32_to_bf16(v0.x);
  o[1] = (short)f32_to_bf16(v0.y);
  o[2] = (short)f32_to_bf16(v0.z);
  o[3] = (short)f32_to_bf16(v0.w);
  o[4] = (short)f32_to_bf16(v1.x);
  o[5] = (short)f32_to_bf16(v1.y);
  o[6] = (short)f32_to_bf16(v1.z);
  o[7] = (short)f32_to_bf16(v1.w);
  *reinterpret_cast<short8*>(xb + i) = o;
}

// ---------------- dequant: bit-planes -> bf16 W[N][K] (validated round 0) ----
__global__ void dequant_kernel(const int* __restrict__ qw,
                               const float* __restrict__ scale,
                               const float* __restrict__ zero,
                               unsigned short* __restrict__ W) {
  int idx = blockIdx.x * blockDim.x + threadIdx.x;   // n*128 + c
  if (idx >= N_DIM * 128) return;
  int n = idx >> 7;
  int c = idx & 127;
  unsigned int w[8];
#pragma unroll
  for (int k = 0; k < 8; ++k)
    w[k] = (unsigned int)qw[(size_t)k * (N_DIM * 128) + idx];
  int wp = c >> 5, t = c & 31;
#pragma unroll
  for (int s = 0; s < 4; ++s) {
    int r = s ^ 3;
    unsigned int by[8];
#pragma unroll
    for (int k = 0; k < 8; ++k) by[k] = (w[k] >> (8 * r)) & 0xffu;
    int ibase = wp * 1024 + s * 256 + t * 8;
    int g = ibase >> 7;
    float sc = scale[n * 32 + g];
    float zp = zero[n * 32 + g] * 16.0f;
    short8 o;
#pragma unroll
    for (int u = 0; u < 8; ++u) {
      unsigned int q = 0;
#pragma unroll
      for (int k = 0; k < 8; ++k)
        q |= ((by[k] >> (7 - u)) & 1u) << (7 - k);
      o[u] = (short)f32_to_bf16(sc * ((float)q - zp));
    }
    *reinterpret_cast<short8*>(&W[(size_t)n * K_DIM + ibase]) = o;
  }
}

// ---------------- 256x256 8-phase bf16 GEMM (T1+T2+T3+T4+T5) ----------------
// C[M][N] = A[M][K] * B[N][K]^T + bias.
// 8 waves (2M x 4N); wave output 128x64; per-phase: one C-quadrant x K=64.
// LDS halves: A half h = tile rows [h*128,+128), B half h = tile cols [h*128,+128).
// Stage: linear LDS dest + inverse-swizzled global src; read: addr ^ (row&7)<<4.

// stage one 128x64 bf16 half-region (16 KB) = 2 x global_load_lds(16B)
static __device__ __forceinline__ void stage_half(
    const unsigned short* __restrict__ G, int grow_base, int k0,
    char* lds_region, int tid) {
#pragma unroll
  for (int i = 0; i < 2; ++i) {
    int lr = i * 64 + (tid >> 3);
    int sslot = (tid & 7) ^ (lr & 7);                 // inverse swizzle on source
    const unsigned short* src = G + (size_t)(grow_base + lr) * K_DIM + k0 + sslot * 8;
    __builtin_amdgcn_global_load_lds(
        (const __attribute__((address_space(1))) void*)src,
        (__attribute__((address_space(3))) void*)(lds_region + i * 8192 + (tid >> 6) * 1024),
        16, 0, 0);                                    // wave-uniform dest + lane*16
  }
}

#define VMCNT4 asm volatile("s_waitcnt vmcnt(4)" ::: "memory")
#define VMCNT0 asm volatile("s_waitcnt vmcnt(0)" ::: "memory")
#define NOOP ((void)0)

#define LDS_A(BUF, H) (smem + ((BUF)*2 + (H)) * 16384)
#define LDS_B(BUF, H) (smem + 65536 + ((BUF)*2 + (H)) * 16384)
#define STG_A(BUF, H, KT) stage_half(Ag, m0 + (H)*128, (KT)*64, LDS_A(BUF, H), tid)
#define STG_B(BUF, H, KT) stage_half(Bg, n0 + (H)*128, (KT)*64, LDS_B(BUF, H), tid)

// one phase: 12 ds_read_b128 || stage || bar || lgkm0 || 16 MFMA || tail || bar
#define PHASE(BUF, QM, QN, STAGE, TAIL) do {                                   \
  short8 a_[4][2], b_[2][2];                                                   \
  const char* Ab_ = LDS_A(BUF, QM);                                            \
  const char* Bb_ = LDS_B(BUF, QN);                                            \
  _Pragma("unroll") for (int mf_ = 0; mf_ < 4; ++mf_) {                        \
    int lr_ = wrbase + mf_ * 16;                                               \
    _Pragma("unroll") for (int kk_ = 0; kk_ < 2; ++kk_)                        \
      a_[mf_][kk_] = *(const short8*)(Ab_ +                                    \
          ((((lr_) << 7) | ((kk_) << 6) | hi4) ^ xorv));                       \
  }                                                                            \
  _Pragma("unroll") for (int nf_ = 0; nf_ < 2; ++nf_) {                        \
    int lc_ = wcbase + nf_ * 16;                                               \
    _Pragma("unroll") for (int kk_ = 0; kk_ < 2; ++kk_)                        \
      b_[nf_][kk_] = *(const short8*)(Bb_ +                                    \
          ((((lc_) << 7) | ((kk_) << 6) | hi4) ^ xorv));                       \
  }                                                                            \
  STAGE;                                                                       \
  __builtin_amdgcn_s_barrier();                                                \
  asm volatile("s_waitcnt lgkmcnt(0)" ::: "memory");                           \
  __builtin_amdgcn_sched_barrier(0);                                           \
  __builtin_amdgcn_s_setprio(1);                                               \
  _Pragma("unroll") for (int mf_ = 0; mf_ < 4; ++mf_)                          \
    _Pragma("unroll") for (int nf_ = 0; nf_ < 2; ++nf_)                        \
      _Pragma("unroll") for (int kk_ = 0; kk_ < 2; ++kk_)                      \
        acc[QM][QN][mf_][nf_] = __builtin_amdgcn_mfma_f32_16x16x32_bf16(       \
            a_[mf_][kk_], b_[nf_][kk_], acc[QM][QN][mf_][nf_], 0, 0, 0);       \
  __builtin_amdgcn_s_setprio(0);                                               \
  TAIL;                                                                        \
  __builtin_amdgcn_s_barrier();                                                \
} while (0)

__global__ __launch_bounds__(512, 2) void gemm_kernel(
    const unsigned short* __restrict__ Ag,   // Xb [M][K] bf16
    const unsigned short* __restrict__ Bg,   // Wb [N][K] bf16
    const float* __restrict__ bias,
    float* __restrict__ C) {
  __shared__ __align__(16) char smem[131072];   // 128 KiB: A 64K + B 64K

  // XCD-aware bijective swizzle: 512 blocks % 8 == 0
  int bid = blockIdx.x;
  int cpx = gridDim.x >> 3;
  int swz = (bid & 7) * cpx + (bid >> 3);
  int tm = swz >> 4;                 // 32 M-tiles (consecutive swz share A-panel)
  int tn = swz & 15;                 // 16 N-tiles
  int m0 = tm * BM, n0 = tn * BN;

  int tid = threadIdx.x;
  int lane = tid & 63;
  int wid = tid >> 6;                // 8 waves
  int wr = wid >> 2, wc = wid & 3;   // 2 x 4

  const int xorv = (lane & 7) << 4;           // T2 read-side swizzle
  const int hi4 = (lane >> 4) << 4;           // k-slot byte offset within frag
  const int wrbase = wr * 64 + (lane & 15);   // local A row (quadrant adds qm*128)
  const int wcbase = wc * 32 + (lane & 15);   // local B col (quadrant adds qn*128)

  f32x4 acc[2][2][4][2];
#pragma unroll
  for (int i = 0; i < 2; ++i)
#pragma unroll
    for (int j = 0; j < 2; ++j)
#pragma unroll
      for (int mf = 0; mf < 4; ++mf)
#pragma unroll
        for (int nf = 0; nf < 2; ++nf) acc[i][j][mf][nf] = (f32x4){0.f, 0.f, 0.f, 0.f};

  // prologue: K-tile 0 all 4 halves, then K-tile 1 A0,B0; land the first 4.
  STG_A(0, 0, 0); STG_A(0, 1, 0); STG_B(0, 0, 0); STG_B(0, 1, 0);
  STG_A(1, 0, 1); STG_B(1, 0, 1);
  VMCNT4;                            // 12 outstanding -> oldest 8 (K-tile 0) landed
  __builtin_amdgcn_s_barrier();

  for (int t = 0; t < 31; ++t) {
    const int kt1 = 2 * t + 1;       // this iteration: K-tiles kt1-1 (buf0), kt1 (buf1)
    PHASE(0, 0, 0, STG_A(1, 1, kt1),     NOOP);    // stage b1A1 <- kt1
    PHASE(0, 0, 1, STG_B(1, 1, kt1),     NOOP);    // stage b1B1 <- kt1
    PHASE(0, 1, 0, STG_A(0, 0, kt1 + 1), NOOP);    // stage b0A0 <- kt1+1
    PHASE(0, 1, 1, STG_B(0, 0, kt1 + 1), VMCNT4);  // b1 K-tile fully landed
    PHASE(1, 0, 0, STG_A(0, 1, kt1 + 1), NOOP);    // stage b0A1
    PHASE(1, 0, 1, STG_B(0, 1, kt1 + 1), NOOP);    // stage b0B1
    PHASE(1, 1, 0, STG_A(1, 0, kt1 + 2), NOOP);    // stage b1A0 <- kt1+2
    PHASE(1, 1, 1, STG_B(1, 0, kt1 + 2), VMCNT4);  // b0 K-tile fully landed
  }
  // peeled last iteration: K-tiles 62 (buf0), 63 (buf1); no OOB stages
  PHASE(0, 0, 0, STG_A(1, 1, 63), NOOP);
  PHASE(0, 0, 1, STG_B(1, 1, 63), NOOP);
  PHASE(0, 1, 0, NOOP,            NOOP);
  PHASE(0, 1, 1, NOOP,            VMCNT0);         // all of K-tile 63 landed
  PHASE(1, 0, 0, NOOP, NOOP);
  PHASE(1, 0, 1, NOOP, NOOP);
  PHASE(1, 1, 0, NOOP, NOOP);
  PHASE(1, 1, 1, NOOP, NOOP);

  // epilogue: C/D layout col=lane&15, row=(lane>>4)*4+j
#pragma unroll
  for (int qn = 0; qn < 2; ++qn)
#pragma unroll
    for (int nf = 0; nf < 2; ++nf) {
      int gcol = n0 + qn * 128 + wc * 32 + nf * 16 + (lane & 15);
      float bv = bias[gcol];
#pragma unroll
      for (int qm = 0; qm < 2; ++qm)
#pragma unroll
        for (int mf = 0; mf < 4; ++mf) {
          int grow = m0 + qm * 128 + wr * 64 + mf * 16 + ((lane >> 4) << 2);
          f32x4 v = acc[qm][qn][mf][nf];
#pragma unroll
          for (int j = 0; j < 4; ++j)
            C[(size_t)(grow + j) * N_DIM + gcol] = v[j] + bv;
        }
    }
}

extern "C" void kernel_launch(void* const* d_in, const int* in_sizes, int n_in,
                              void* d_out, int out_size, void* d_ws, size_t ws_size,
                              hipStream_t stream) {
  const float* x       = (const float*)d_in[0];
  const int*   qweight = (const int*)d_in[1];
  const float* scale   = (const float*)d_in[2];
  const float* zero    = (const float*)d_in[3];
  const float* bias    = (const float*)d_in[4];
  float* out = (float*)d_out;

  unsigned short* Xb = (unsigned short*)d_ws;                    // 64 MB
  unsigned short* Wb = Xb + (size_t)M_DIM * K_DIM;               // 32 MB

  cast_x_kernel<<<(M_DIM * K_DIM / 8) / 256, 256, 0, stream>>>(x, Xb);
  dequant_kernel<<<(N_DIM * 128) / 256, 256, 0, stream>>>(qweight, scale, zero, Wb);
  gemm_kernel<<<(M_DIM / BM) * (N_DIM / BN), 512, 0, stream>>>(Xb, Wb, bias, out);
}

// Round 3
// 277.388 us; speedup vs baseline: 1.5874x; 1.0855x over previous
//
#include <hip/hip_runtime.h>
#include <hip/hip_bf16.h>
#include <stdint.h>

typedef __attribute__((ext_vector_type(8))) short short8;
typedef __attribute__((ext_vector_type(4))) float f32x4;

#define M_DIM 8192
#define N_DIM 4096
#define K_DIM 4096
#define BM 256
#define BN 256
#define BK 64

static __device__ __forceinline__ unsigned short f32_to_bf16(float f) {
  union { float f; unsigned int u; } v; v.f = f;
  unsigned int u = v.u;
  u += 0x7fffu + ((u >> 16) & 1u);   // round-to-nearest-even
  return (unsigned short)(u >> 16);
}

// ---------------- cast x (f32 -> bf16), 8 elems/thread ----------------
__global__ void cast_x_kernel(const float* __restrict__ x,
                              unsigned short* __restrict__ xb) {
  size_t i = ((size_t)blockIdx.x * blockDim.x + threadIdx.x) * 8;
  if (i >= (size_t)M_DIM * K_DIM) return;
  float4 v0 = *reinterpret_cast<const float4*>(x + i);
  float4 v1 = *reinterpret_cast<const float4*>(x + i + 4);
  short8 o;
  o[0] = (short)f32_to_bf16(v0.x);
  o[1] = (short)f32_to_bf16(v0.y);
  o[2] = (short)f32_to_bf16(v0.z);
  o[3] = (short)f32_to_bf16(v0.w);
  o[4] = (short)f32_to_bf16(v1.x);
  o[5] = (short)f32_to_bf16(v1.y);
  o[6] = (short)f32_to_bf16(v1.z);
  o[7] = (short)f32_to_bf16(v1.w);
  *reinterpret_cast<short8*>(xb + i) = o;
}

// ---------------- dequant: bit-planes -> bf16 W[N][K] (validated) ----------
__global__ void dequant_kernel(const int* __restrict__ qw,
                               const float* __restrict__ scale,
                               const float* __restrict__ zero,
                               unsigned short* __restrict__ W) {
  int idx = blockIdx.x * blockDim.x + threadIdx.x;   // n*128 + c
  if (idx >= N_DIM * 128) return;
  int n = idx >> 7;
  int c = idx & 127;
  unsigned int w[8];
#pragma unroll
  for (int k = 0; k < 8; ++k)
    w[k] = (unsigned int)qw[(size_t)k * (N_DIM * 128) + idx];
  int wp = c >> 5, t = c & 31;
#pragma unroll
  for (int s = 0; s < 4; ++s) {
    int r = s ^ 3;
    unsigned int by[8];
#pragma unroll
    for (int k = 0; k < 8; ++k) by[k] = (w[k] >> (8 * r)) & 0xffu;
    int ibase = wp * 1024 + s * 256 + t * 8;
    int g = ibase >> 7;
    float sc = scale[n * 32 + g];
    float zp = zero[n * 32 + g] * 16.0f;
    short8 o;
#pragma unroll
    for (int u = 0; u < 8; ++u) {
      unsigned int q = 0;
#pragma unroll
      for (int k = 0; k < 8; ++k)
        q |= ((by[k] >> (7 - u)) & 1u) << (7 - k);
      o[u] = (short)f32_to_bf16(sc * ((float)q - zp));
    }
    *reinterpret_cast<short8*>(&W[(size_t)n * K_DIM + ibase]) = o;
  }
}

// ---------- 256x256 8-phase bf16 GEMM, Gray-code operand reuse ----------
// C[M][N] = A[M][K] * B[N][K]^T + bias. 8 waves (2Mx4N), wave out 128x64.
// Phase quadrant order per buf: (0,0)->(0,1)->(1,1)->(1,0); A frags live 2
// phases, B reloaded per phase. ds_read_b128: 12,4,8,4 per buf (28/K-tile).
// LDS-read phases per half: b0: A0@1 B0@1,4 B1@2 A1@3 ; b1: +4. Stages are
// placed >=1 phase after the target's last read; counted vmcnt(2) at ph4/ph8.

static __device__ __forceinline__ void stage_half(
    const unsigned short* __restrict__ G, int grow_base, int k0,
    char* lds_region, int tid) {
#pragma unroll
  for (int i = 0; i < 2; ++i) {
    int lr = i * 64 + (tid >> 3);
    int sslot = (tid & 7) ^ (lr & 7);                 // inverse swizzle on source
    const unsigned short* src = G + (size_t)(grow_base + lr) * K_DIM + k0 + sslot * 8;
    __builtin_amdgcn_global_load_lds(
        (const __attribute__((address_space(1))) void*)src,
        (__attribute__((address_space(3))) void*)(lds_region + i * 8192 + (tid >> 6) * 1024),
        16, 0, 0);                                    // wave-uniform dest + lane*16
  }
}

#define VMCNT2 asm volatile("s_waitcnt vmcnt(2)" ::: "memory")
#define VMCNT0 asm volatile("s_waitcnt vmcnt(0)" ::: "memory")
#define LGKM8  asm volatile("s_waitcnt lgkmcnt(8)" ::: "memory")
#define NOOP ((void)0)

#define LDS_A(BUF, H) (smem + ((BUF)*2 + (H)) * 16384)
#define LDS_B(BUF, H) (smem + 65536 + ((BUF)*2 + (H)) * 16384)
#define STG_A(BUF, H, KT) stage_half(Ag, m0 + (H)*128, (KT)*64, LDS_A(BUF, H), tid)
#define STG_B(BUF, H, KT) stage_half(Bg, n0 + (H)*128, (KT)*64, LDS_B(BUF, H), tid)

#define LOAD_A(BUF, QM) do {                                                   \
  const char* Ab_ = LDS_A(BUF, QM);                                            \
  _Pragma("unroll") for (int mf_ = 0; mf_ < 4; ++mf_) {                        \
    int lr_ = wrbase + mf_ * 16;                                               \
    _Pragma("unroll") for (int kk_ = 0; kk_ < 2; ++kk_)                        \
      a_[mf_][kk_] = *(const short8*)(Ab_ +                                    \
          ((((lr_) << 7) | ((kk_) << 6) | hi4) ^ xorv));                       \
  } } while (0)

#define LOAD_B(BUF, QN) do {                                                   \
  const char* Bb_ = LDS_B(BUF, QN);                                            \
  _Pragma("unroll") for (int nf_ = 0; nf_ < 2; ++nf_) {                        \
    int lc_ = wcbase + nf_ * 16;                                               \
    _Pragma("unroll") for (int kk_ = 0; kk_ < 2; ++kk_)                        \
      b_[nf_][kk_] = *(const short8*)(Bb_ +                                    \
          ((((lc_) << 7) | ((kk_) << 6) | hi4) ^ xorv));                       \
  } } while (0)

// one phase: ds-reads || stage || bar || lgkm0 || 16 MFMA || tail || bar
#define PHASE(LOADS, QM, QN, STAGE, TAIL) do {                                 \
  LOADS;                                                                       \
  STAGE;                                                                       \
  __builtin_amdgcn_s_barrier();                                                \
  asm volatile("s_waitcnt lgkmcnt(0)" ::: "memory");                           \
  __builtin_amdgcn_sched_barrier(0);                                           \
  __builtin_amdgcn_s_setprio(1);                                               \
  _Pragma("unroll") for (int mf_ = 0; mf_ < 4; ++mf_)                          \
    _Pragma("unroll") for (int nf_ = 0; nf_ < 2; ++nf_)                        \
      _Pragma("unroll") for (int kk_ = 0; kk_ < 2; ++kk_)                      \
        acc[QM][QN][mf_][nf_] = __builtin_amdgcn_mfma_f32_16x16x32_bf16(       \
            a_[mf_][kk_], b_[nf_][kk_], acc[QM][QN][mf_][nf_], 0, 0, 0);       \
  __builtin_amdgcn_s_setprio(0);                                               \
  TAIL;                                                                        \
  __builtin_amdgcn_s_barrier();                                                \
} while (0)

__global__ __launch_bounds__(512, 2) void gemm_kernel(
    const unsigned short* __restrict__ Ag,   // Xb [M][K] bf16
    const unsigned short* __restrict__ Bg,   // Wb [N][K] bf16
    const float* __restrict__ bias,
    float* __restrict__ C) {
  __shared__ __align__(16) char smem[131072];   // 128 KiB: A 64K + B 64K

  // XCD-aware bijective swizzle: 512 blocks % 8 == 0
  int bid = blockIdx.x;
  int cpx = gridDim.x >> 3;
  int swz = (bid & 7) * cpx + (bid >> 3);
  int tm = swz >> 4;                 // 32 M-tiles
  int tn = swz & 15;                 // 16 N-tiles
  int m0 = tm * BM, n0 = tn * BN;

  int tid = threadIdx.x;
  int lane = tid & 63;
  int wid = tid >> 6;                // 8 waves
  int wr = wid >> 2, wc = wid & 3;   // 2 x 4

  const int xorv = (lane & 7) << 4;           // T2 read-side swizzle
  const int hi4 = (lane >> 4) << 4;           // k-slot byte offset within frag
  const int wrbase = wr * 64 + (lane & 15);
  const int wcbase = wc * 32 + (lane & 15);

  short8 a_[4][2], b_[2][2];                  // operand frags, reused across phases
  f32x4 acc[2][2][4][2];
#pragma unroll
  for (int i = 0; i < 2; ++i)
#pragma unroll
    for (int j = 0; j < 2; ++j)
#pragma unroll
      for (int mf = 0; mf < 4; ++mf)
#pragma unroll
        for (int nf = 0; nf < 2; ++nf) acc[i][j][mf][nf] = (f32x4){0.f, 0.f, 0.f, 0.f};

  // prologue: buf0 <- K-tile 0 (4 halves), buf1 A0 <- K-tile 1; land first 4.
  STG_A(0, 0, 0); STG_A(0, 1, 0); STG_B(0, 0, 0); STG_B(0, 1, 0);
  STG_A(1, 0, 1);
  VMCNT2;
  __builtin_amdgcn_s_barrier();

  for (int t = 0; t < 31; ++t) {
    const int kt1 = 2 * t + 1;     // buf0 = kt1-1, buf1 = kt1
    PHASE(LOAD_A(0,0); LOAD_B(0,0), 0, 0, STG_B(1,0,kt1); LGKM8, NOOP);
    PHASE(LOAD_B(0,1),              0, 1, STG_A(1,1,kt1),        NOOP);
    PHASE(LOAD_A(0,1),              1, 1, STG_B(1,1,kt1),        NOOP);
    PHASE(LOAD_B(0,0),              1, 0, STG_A(0,0,kt1+1),      VMCNT2);
    PHASE(LOAD_A(1,0); LOAD_B(1,0), 0, 0, STG_B(0,1,kt1+1); LGKM8, NOOP);
    PHASE(LOAD_B(1,1),              0, 1, STG_A(0,1,kt1+1),      NOOP);
    PHASE(LOAD_A(1,1),              1, 1, STG_B(0,0,kt1+1),      NOOP);
    PHASE(LOAD_B(1,0),              1, 0, STG_A(1,0,kt1+2),      VMCNT2);
  }
  // peeled last iteration: buf0 = 62, buf1 = 63; no OOB stages
  PHASE(LOAD_A(0,0); LOAD_B(0,0), 0, 0, STG_B(1,0,63); LGKM8, NOOP);
  PHASE(LOAD_B(0,1),              0, 1, STG_A(1,1,63),        NOOP);
  PHASE(LOAD_A(0,1),              1, 1, STG_B(1,1,63),        NOOP);
  PHASE(LOAD_B(0,0),              1, 0, NOOP,                 VMCNT0);
  PHASE(LOAD_A(1,0); LOAD_B(1,0), 0, 0, NOOP, NOOP);
  PHASE(LOAD_B(1,1),              0, 1, NOOP, NOOP);
  PHASE(LOAD_A(1,1),              1, 1, NOOP, NOOP);
  PHASE(LOAD_B(1,0),              1, 0, NOOP, NOOP);

  // epilogue: C/D layout col=lane&15, row=(lane>>4)*4+j
#pragma unroll
  for (int qn = 0; qn < 2; ++qn)
#pragma unroll
    for (int nf = 0; nf < 2; ++nf) {
      int gcol = n0 + qn * 128 + wc * 32 + nf * 16 + (lane & 15);
      float bv = bias[gcol];
#pragma unroll
      for (int qm = 0; qm < 2; ++qm)
#pragma unroll
        for (int mf = 0; mf < 4; ++mf) {
          int grow = m0 + qm * 128 + wr * 64 + mf * 16 + ((lane >> 4) << 2);
          f32x4 v = acc[qm][qn][mf][nf];
#pragma unroll
          for (int j = 0; j < 4; ++j)
            C[(size_t)(grow + j) * N_DIM + gcol] = v[j] + bv;
        }
    }
}

extern "C" void kernel_launch(void* const* d_in, const int* in_sizes, int n_in,
                              void* d_out, int out_size, void* d_ws, size_t ws_size,
                              hipStream_t stream) {
  const float* x       = (const float*)d_in[0];
  const int*   qweight = (const int*)d_in[1];
  const float* scale   = (const float*)d_in[2];
  const float* zero    = (const float*)d_in[3];
  const float* bias    = (const float*)d_in[4];
  float* out = (float*)d_out;

  unsigned short* Xb = (unsigned short*)d_ws;                    // 64 MB
  unsigned short* Wb = Xb + (size_t)M_DIM * K_DIM;               // 32 MB

  cast_x_kernel<<<(M_DIM * K_DIM / 8) / 256, 256, 0, stream>>>(x, Xb);
  dequant_kernel<<<(N_DIM * 128) / 256, 256, 0, stream>>>(qweight, scale, zero, Wb);
  gemm_kernel<<<(M_DIM / BM) * (N_DIM / BN), 512, 0, stream>>>(Xb, Wb, bias, out);
}

// Round 4
// 273.566 us; speedup vs baseline: 1.6096x; 1.0140x over previous
//
#include <hip/hip_runtime.h>
#include <hip/hip_bf16.h>
#include <stdint.h>

typedef __attribute__((ext_vector_type(8))) short short8;
typedef __attribute__((ext_vector_type(4))) float f32x4;

#define M_DIM 8192
#define N_DIM 4096
#define K_DIM 4096
#define BM 256
#define BN 256
#define BK 64

static __device__ __forceinline__ unsigned short f32_to_bf16(float f) {
  union { float f; unsigned int u; } v; v.f = f;
  unsigned int u = v.u;
  u += 0x7fffu + ((u >> 16) & 1u);   // round-to-nearest-even
  return (unsigned short)(u >> 16);
}

// ---------------- cast x (f32 -> bf16), 8 elems/thread ----------------
__global__ void cast_x_kernel(const float* __restrict__ x,
                              unsigned short* __restrict__ xb) {
  size_t i = ((size_t)blockIdx.x * blockDim.x + threadIdx.x) * 8;
  if (i >= (size_t)M_DIM * K_DIM) return;
  float4 v0 = *reinterpret_cast<const float4*>(x + i);
  float4 v1 = *reinterpret_cast<const float4*>(x + i + 4);
  short8 o;
  o[0] = (short)f32_to_bf16(v0.x);
  o[1] = (short)f32_to_bf16(v0.y);
  o[2] = (short)f32_to_bf16(v0.z);
  o[3] = (short)f32_to_bf16(v0.w);
  o[4] = (short)f32_to_bf16(v1.x);
  o[5] = (short)f32_to_bf16(v1.y);
  o[6] = (short)f32_to_bf16(v1.z);
  o[7] = (short)f32_to_bf16(v1.w);
  *reinterpret_cast<short8*>(xb + i) = o;
}

// ---------------- dequant: bit-planes -> bf16 W[N][K] (validated) ----------
__global__ void dequant_kernel(const int* __restrict__ qw,
                               const float* __restrict__ scale,
                               const float* __restrict__ zero,
                               unsigned short* __restrict__ W) {
  int idx = blockIdx.x * blockDim.x + threadIdx.x;   // n*128 + c
  if (idx >= N_DIM * 128) return;
  int n = idx >> 7;
  int c = idx & 127;
  unsigned int w[8];
#pragma unroll
  for (int k = 0; k < 8; ++k)
    w[k] = (unsigned int)qw[(size_t)k * (N_DIM * 128) + idx];
  int wp = c >> 5, t = c & 31;
#pragma unroll
  for (int s = 0; s < 4; ++s) {
    int r = s ^ 3;
    unsigned int by[8];
#pragma unroll
    for (int k = 0; k < 8; ++k) by[k] = (w[k] >> (8 * r)) & 0xffu;
    int ibase = wp * 1024 + s * 256 + t * 8;
    int g = ibase >> 7;
    float sc = scale[n * 32 + g];
    float zp = zero[n * 32 + g] * 16.0f;
    short8 o;
#pragma unroll
    for (int u = 0; u < 8; ++u) {
      unsigned int q = 0;
#pragma unroll
      for (int k = 0; k < 8; ++k)
        q |= ((by[k] >> (7 - u)) & 1u) << (7 - k);
      o[u] = (short)f32_to_bf16(sc * ((float)q - zp));
    }
    *reinterpret_cast<short8*>(&W[(size_t)n * K_DIM + ibase]) = o;
  }
}

// ---------- 256x256 8-phase bf16 GEMM, Gray-code + hoisted addressing -------
// C[M][N] = A[M][K] * B[N][K]^T + bias. 8 waves (2Mx4N), wave out 128x64.
// R4: all lane-varying address math hoisted to loop-invariant VGPRs; ds_reads
// use base-voffset + compile-time imm; stage global addr = uniform scalar +
// fixed lane voffset. Schedule identical to R3 (verified).

#define VMCNT2 asm volatile("s_waitcnt vmcnt(2)" ::: "memory")
#define VMCNT0 asm volatile("s_waitcnt vmcnt(0)" ::: "memory")
#define LGKM8  asm volatile("s_waitcnt lgkmcnt(8)" ::: "memory")
#define NOOP ((void)0)

// stage one 128x64 half-region: 2 x global_load_lds(16B); lane offsets hoisted
#define STG(G, GROWB, KT, LDSC) do {                                           \
  const unsigned short* sb_ = (G) + ((size_t)(GROWB) * K_DIM + (KT) * 64);     \
  __builtin_amdgcn_global_load_lds(                                            \
      (const __attribute__((address_space(1))) void*)(sb_ + s_off0),           \
      (__attribute__((address_space(3))) void*)(smem + (LDSC) + wslot),        \
      16, 0, 0);                                                               \
  __builtin_amdgcn_global_load_lds(                                            \
      (const __attribute__((address_space(1))) void*)(sb_ + s_off1),           \
      (__attribute__((address_space(3))) void*)(smem + (LDSC) + 8192 + wslot), \
      16, 0, 0);                                                               \
} while (0)
#define STG_A(BUF, H, KT) STG(Ag, m0 + (H)*128, (KT), ((BUF)*2 + (H)) * 16384)
#define STG_B(BUF, H, KT) STG(Bg, n0 + (H)*128, (KT), 65536 + ((BUF)*2 + (H)) * 16384)

// ds_read_b128 with hoisted voffset + compile-time immediate (region + frag)
#define LOAD_A(BUF, QM) do {                                                   \
  _Pragma("unroll") for (int mf_ = 0; mf_ < 4; ++mf_) {                        \
    a_[mf_][0] = *(const short8*)(smem + a_off0 +                              \
                                  (((BUF)*2 + (QM)) * 16384 + mf_ * 2048));    \
    a_[mf_][1] = *(const short8*)(smem + a_off1 +                              \
                                  (((BUF)*2 + (QM)) * 16384 + mf_ * 2048));    \
  } } while (0)

#define LOAD_B(BUF, QN) do {                                                   \
  _Pragma("unroll") for (int nf_ = 0; nf_ < 2; ++nf_) {                        \
    b_[nf_][0] = *(const short8*)(smem + b_off0 +                              \
                                  (((BUF)*2 + (QN)) * 16384 + nf_ * 2048));    \
    b_[nf_][1] = *(const short8*)(smem + b_off1 +                              \
                                  (((BUF)*2 + (QN)) * 16384 + nf_ * 2048));    \
  } } while (0)

// one phase: ds-reads || stage || bar || lgkm0 || 16 MFMA || tail || bar
#define PHASE(LOADS, QM, QN, STAGE, TAIL) do {                                 \
  LOADS;                                                                       \
  STAGE;                                                                       \
  __builtin_amdgcn_s_barrier();                                                \
  asm volatile("s_waitcnt lgkmcnt(0)" ::: "memory");                           \
  __builtin_amdgcn_sched_barrier(0);                                           \
  __builtin_amdgcn_s_setprio(1);                                               \
  _Pragma("unroll") for (int mf_ = 0; mf_ < 4; ++mf_)                          \
    _Pragma("unroll") for (int nf_ = 0; nf_ < 2; ++nf_)                        \
      _Pragma("unroll") for (int kk_ = 0; kk_ < 2; ++kk_)                      \
        acc[QM][QN][mf_][nf_] = __builtin_amdgcn_mfma_f32_16x16x32_bf16(       \
            a_[mf_][kk_], b_[nf_][kk_], acc[QM][QN][mf_][nf_], 0, 0, 0);       \
  __builtin_amdgcn_s_setprio(0);                                               \
  TAIL;                                                                        \
  __builtin_amdgcn_s_barrier();                                                \
} while (0)

__global__ __launch_bounds__(512, 2) void gemm_kernel(
    const unsigned short* __restrict__ Ag,   // Xb [M][K] bf16
    const unsigned short* __restrict__ Bg,   // Wb [N][K] bf16
    const float* __restrict__ bias,
    float* __restrict__ C) {
  __shared__ __align__(16) char smem[131072];   // A: [0,64K), B: [64K,128K)

  // XCD-aware bijective swizzle: 512 blocks % 8 == 0
  int bid = blockIdx.x;
  int cpx = gridDim.x >> 3;
  int swz = (bid & 7) * cpx + (bid >> 3);
  int tm = swz >> 4;                 // 32 M-tiles
  int tn = swz & 15;                 // 16 N-tiles
  int m0 = tm * BM, n0 = tn * BN;

  int tid = threadIdx.x;
  int lane = tid & 63;
  int wid = tid >> 6;                // 8 waves
  int wr = wid >> 2, wc = wid & 3;   // 2 x 4

  // ---- hoisted, loop-invariant lane addressing ----
  const int xorv = (lane & 7) << 4;           // T2 read-side swizzle
  const int hi4 = (lane >> 4) << 4;           // k-group byte offset
  const int wrbase = wr * 64 + (lane & 15);
  const int wcbase = wc * 32 + (lane & 15);
  const int a_off0 = (wrbase << 7) + (hi4 ^ xorv);
  const int a_off1 = (wrbase << 7) + ((64 | hi4) ^ xorv);
  const int b_off0 = 65536 + (wcbase << 7) + (hi4 ^ xorv);
  const int b_off1 = 65536 + (wcbase << 7) + ((64 | hi4) ^ xorv);
  const int wslot = (tid >> 6) << 10;         // per-wave 1KB LDS slot
  const int s_lr0 = tid >> 3, s_lr1 = 64 + (tid >> 3);
  const int s_off0 = s_lr0 * K_DIM + (((tid & 7) ^ (s_lr0 & 7)) << 3);
  const int s_off1 = s_lr1 * K_DIM + (((tid & 7) ^ (s_lr1 & 7)) << 3);

  short8 a_[4][2], b_[2][2];                  // operand frags, reused across phases
  f32x4 acc[2][2][4][2];
#pragma unroll
  for (int i = 0; i < 2; ++i)
#pragma unroll
    for (int j = 0; j < 2; ++j)
#pragma unroll
      for (int mf = 0; mf < 4; ++mf)
#pragma unroll
        for (int nf = 0; nf < 2; ++nf) acc[i][j][mf][nf] = (f32x4){0.f, 0.f, 0.f, 0.f};

  // prologue: buf0 <- K-tile 0 (4 halves), buf1 A0 <- K-tile 1; land first 4.
  STG_A(0, 0, 0); STG_A(0, 1, 0); STG_B(0, 0, 0); STG_B(0, 1, 0);
  STG_A(1, 0, 1);
  VMCNT2;
  __builtin_amdgcn_s_barrier();

  for (int t = 0; t < 31; ++t) {
    const int kt1 = 2 * t + 1;     // buf0 = kt1-1, buf1 = kt1
    PHASE(LOAD_A(0,0); LOAD_B(0,0), 0, 0, STG_B(1,0,kt1); LGKM8, NOOP);
    PHASE(LOAD_B(0,1),              0, 1, STG_A(1,1,kt1),        NOOP);
    PHASE(LOAD_A(0,1),              1, 1, STG_B(1,1,kt1),        NOOP);
    PHASE(LOAD_B(0,0),              1, 0, STG_A(0,0,kt1+1),      VMCNT2);
    PHASE(LOAD_A(1,0); LOAD_B(1,0), 0, 0, STG_B(0,1,kt1+1); LGKM8, NOOP);
    PHASE(LOAD_B(1,1),              0, 1, STG_A(0,1,kt1+1),      NOOP);
    PHASE(LOAD_A(1,1),              1, 1, STG_B(0,0,kt1+1),      NOOP);
    PHASE(LOAD_B(1,0),              1, 0, STG_A(1,0,kt1+2),      VMCNT2);
  }
  // peeled last iteration: buf0 = 62, buf1 = 63; no OOB stages
  PHASE(LOAD_A(0,0); LOAD_B(0,0), 0, 0, STG_B(1,0,63); LGKM8, NOOP);
  PHASE(LOAD_B(0,1),              0, 1, STG_A(1,1,63),        NOOP);
  PHASE(LOAD_A(0,1),              1, 1, STG_B(1,1,63),        NOOP);
  PHASE(LOAD_B(0,0),              1, 0, NOOP,                 VMCNT0);
  PHASE(LOAD_A(1,0); LOAD_B(1,0), 0, 0, NOOP, NOOP);
  PHASE(LOAD_B(1,1),              0, 1, NOOP, NOOP);
  PHASE(LOAD_A(1,1),              1, 1, NOOP, NOOP);
  PHASE(LOAD_B(1,0),              1, 0, NOOP, NOOP);

  // epilogue: C/D layout col=lane&15, row=(lane>>4)*4+j
#pragma unroll
  for (int qn = 0; qn < 2; ++qn)
#pragma unroll
    for (int nf = 0; nf < 2; ++nf) {
      int gcol = n0 + qn * 128 + wc * 32 + nf * 16 + (lane & 15);
      float bv = bias[gcol];
#pragma unroll
      for (int qm = 0; qm < 2; ++qm)
#pragma unroll
        for (int mf = 0; mf < 4; ++mf) {
          int grow = m0 + qm * 128 + wr * 64 + mf * 16 + ((lane >> 4) << 2);
          f32x4 v = acc[qm][qn][mf][nf];
#pragma unroll
          for (int j = 0; j < 4; ++j)
            C[(size_t)(grow + j) * N_DIM + gcol] = v[j] + bv;
        }
    }
}

extern "C" void kernel_launch(void* const* d_in, const int* in_sizes, int n_in,
                              void* d_out, int out_size, void* d_ws, size_t ws_size,
                              hipStream_t stream) {
  const float* x       = (const float*)d_in[0];
  const int*   qweight = (const int*)d_in[1];
  const float* scale   = (const float*)d_in[2];
  const float* zero    = (const float*)d_in[3];
  const float* bias    = (const float*)d_in[4];
  float* out = (float*)d_out;

  unsigned short* Xb = (unsigned short*)d_ws;                    // 64 MB
  unsigned short* Wb = Xb + (size_t)M_DIM * K_DIM;               // 32 MB

  cast_x_kernel<<<(M_DIM * K_DIM / 8) / 256, 256, 0, stream>>>(x, Xb);
  dequant_kernel<<<(N_DIM * 128) / 256, 256, 0, stream>>>(qweight, scale, zero, Wb);
  gemm_kernel<<<(M_DIM / BM) * (N_DIM / BN), 512, 0, stream>>>(Xb, Wb, bias, out);
}

// Round 6
// 262.978 us; speedup vs baseline: 1.6744x; 1.0403x over previous
//
#include <hip/hip_runtime.h>
#include <hip/hip_bf16.h>
#include <stdint.h>

typedef __attribute__((ext_vector_type(8))) short short8;
typedef __attribute__((ext_vector_type(4))) float f32x4;

#define M_DIM 8192
#define N_DIM 4096
#define K_DIM 4096
#define BM 256
#define BN 256
#define BK 64

static __device__ __forceinline__ unsigned short f32_to_bf16(float f) {
  union { float f; unsigned int u; } v; v.f = f;
  unsigned int u = v.u;
  u += 0x7fffu + ((u >> 16) & 1u);   // round-to-nearest-even
  return (unsigned short)(u >> 16);
}

// ---------------- cast x (f32 -> bf16), 8 elems/thread ----------------
__global__ void cast_x_kernel(const float* __restrict__ x,
                              unsigned short* __restrict__ xb) {
  size_t i = ((size_t)blockIdx.x * blockDim.x + threadIdx.x) * 8;
  if (i >= (size_t)M_DIM * K_DIM) return;
  float4 v0 = *reinterpret_cast<const float4*>(x + i);
  float4 v1 = *reinterpret_cast<const float4*>(x + i + 4);
  short8 o;
  o[0] = (short)f32_to_bf16(v0.x);
  o[1] = (short)f32_to_bf16(v0.y);
  o[2] = (short)f32_to_bf16(v0.z);
  o[3] = (short)f32_to_bf16(v0.w);
  o[4] = (short)f32_to_bf16(v1.x);
  o[5] = (short)f32_to_bf16(v1.y);
  o[6] = (short)f32_to_bf16(v1.z);
  o[7] = (short)f32_to_bf16(v1.w);
  *reinterpret_cast<short8*>(xb + i) = o;
}

// ---------------- dequant: bit-planes -> bf16 W[N][K] (validated) ----------
__global__ void dequant_kernel(const int* __restrict__ qw,
                               const float* __restrict__ scale,
                               const float* __restrict__ zero,
                               unsigned short* __restrict__ W) {
  int idx = blockIdx.x * blockDim.x + threadIdx.x;   // n*128 + c
  if (idx >= N_DIM * 128) return;
  int n = idx >> 7;
  int c = idx & 127;
  unsigned int w[8];
#pragma unroll
  for (int k = 0; k < 8; ++k)
    w[k] = (unsigned int)qw[(size_t)k * (N_DIM * 128) + idx];
  int wp = c >> 5, t = c & 31;
#pragma unroll
  for (int s = 0; s < 4; ++s) {
    int r = s ^ 3;
    unsigned int by[8];
#pragma unroll
    for (int k = 0; k < 8; ++k) by[k] = (w[k] >> (8 * r)) & 0xffu;
    int ibase = wp * 1024 + s * 256 + t * 8;
    int g = ibase >> 7;
    float sc = scale[n * 32 + g];
    float zp = zero[n * 32 + g] * 16.0f;
    short8 o;
#pragma unroll
    for (int u = 0; u < 8; ++u) {
      unsigned int q = 0;
#pragma unroll
      for (int k = 0; k < 8; ++k)
        q |= ((by[k] >> (7 - u)) & 1u) << (7 - k);
      o[u] = (short)f32_to_bf16(sc * ((float)q - zp));
    }
    *reinterpret_cast<short8*>(&W[(size_t)n * K_DIM + ibase]) = o;
  }
}

// ---- 256x256 8-region bf16 GEMM: reads one-phase-ahead inside MFMA region ----
// C[M][N] = A[M][K] * B[N][K]^T + bias. 8 waves (2Mx4N), wave out 128x64.
// Region p: bar; vmcnt(2); lgkm(0); SB0; prio1; {stage || kk0-MFMA || rd(p+1,kk0)};
//           SB0; {kk1-MFMA || rd(p+1,kk1)}; prio0.
// VISIBILITY RULE (R5 NaN post-mortem): each wave stages 1KB of every 16KB
// region but reads all waves' slots; vmcnt is per-wave. Data staged at region
// s is readable only after every wave's covering vmcnt-drain is followed by a
// barrier that precedes the read. Ledger (steady state, prologue leaves only
// A10 in flight): drain(s) at region s+1..s+2 entry, read at >= s+3 — every
// edge has drain -> barrier -> read. Prologue: vmcnt(2)+s_barrier BEFORE the
// first ds_reads (this was the R5 race). Peel: drain moved to p5 (vmcnt(0)).

#define VMCNT2 asm volatile("s_waitcnt vmcnt(2)" ::: "memory")
#define VMCNT0 asm volatile("s_waitcnt vmcnt(0)" ::: "memory")
#define NOOP ((void)0)

#define STG(G, GROWB, KT, LDSC) do {                                           \
  const unsigned short* sb_ = (G) + ((size_t)(GROWB) * K_DIM + (KT) * 64);     \
  __builtin_amdgcn_global_load_lds(                                            \
      (const __attribute__((address_space(1))) void*)(sb_ + s_off0),           \
      (__attribute__((address_space(3))) void*)(smem + (LDSC) + wslot),        \
      16, 0, 0);                                                               \
  __builtin_amdgcn_global_load_lds(                                            \
      (const __attribute__((address_space(1))) void*)(sb_ + s_off1),           \
      (__attribute__((address_space(3))) void*)(smem + (LDSC) + 8192 + wslot), \
      16, 0, 0);                                                               \
} while (0)
#define STG_A(BUF, H, KT) STG(Ag, m0 + (H)*128, (KT), ((BUF)*2 + (H)) * 16384)
#define STG_B(BUF, H, KT) STG(Bg, n0 + (H)*128, (KT), 65536 + ((BUF)*2 + (H)) * 16384)

// reads for ONE k-slot (KK literal): 4 A-frags or 2 B-frags
#define LA(BUF, QM, KK) do {                                                   \
  _Pragma("unroll") for (int mf_ = 0; mf_ < 4; ++mf_)                          \
    a_[mf_][KK] = *(const short8*)(smem + ((KK) ? a_off1 : a_off0) +           \
        (((BUF)*2 + (QM)) * 16384 + mf_ * 2048));                              \
} while (0)
#define LB(BUF, QN, KK) do {                                                   \
  _Pragma("unroll") for (int nf_ = 0; nf_ < 2; ++nf_)                          \
    b_[nf_][KK] = *(const short8*)(smem + ((KK) ? b_off1 : b_off0) +           \
        (((BUF)*2 + (QN)) * 16384 + nf_ * 2048));                              \
} while (0)

#define MFMA_KK(QM, QN, KK)                                                    \
  _Pragma("unroll") for (int mf_ = 0; mf_ < 4; ++mf_)                          \
    _Pragma("unroll") for (int nf_ = 0; nf_ < 2; ++nf_)                        \
      acc[QM][QN][mf_][nf_] = __builtin_amdgcn_mfma_f32_16x16x32_bf16(         \
          a_[mf_][KK], b_[nf_][KK], acc[QM][QN][mf_][nf_], 0, 0, 0)

// one region; RD0/RD1 load operands for the NEXT region's MFMAs
#define REGION(QM, QN, RD0, RD1, STAGE, WAITV) do {                            \
  __builtin_amdgcn_s_barrier();                                                \
  WAITV;                                                                       \
  asm volatile("s_waitcnt lgkmcnt(0)" ::: "memory");                           \
  __builtin_amdgcn_sched_barrier(0);                                           \
  __builtin_amdgcn_s_setprio(1);                                               \
  STAGE;                                                                       \
  MFMA_KK(QM, QN, 0);                                                          \
  RD0;                                                                         \
  __builtin_amdgcn_sched_barrier(0);                                           \
  MFMA_KK(QM, QN, 1);                                                          \
  RD1;                                                                         \
  __builtin_amdgcn_s_setprio(0);                                               \
} while (0)

__global__ __launch_bounds__(512, 2) void gemm_kernel(
    const unsigned short* __restrict__ Ag,   // Xb [M][K] bf16
    const unsigned short* __restrict__ Bg,   // Wb [N][K] bf16
    const float* __restrict__ bias,
    float* __restrict__ C) {
  __shared__ __align__(16) char smem[131072];   // A: [0,64K), B: [64K,128K)

  // XCD-aware bijective swizzle: 512 blocks % 8 == 0
  int bid = blockIdx.x;
  int cpx = gridDim.x >> 3;
  int swz = (bid & 7) * cpx + (bid >> 3);
  int tm = swz >> 4;                 // 32 M-tiles
  int tn = swz & 15;                 // 16 N-tiles
  int m0 = tm * BM, n0 = tn * BN;

  int tid = threadIdx.x;
  int lane = tid & 63;
  int wid = tid >> 6;                // 8 waves
  int wr = wid >> 2, wc = wid & 3;   // 2 x 4

  // hoisted lane addressing (R4, validated)
  const int xorv = (lane & 7) << 4;
  const int hi4 = (lane >> 4) << 4;
  const int wrbase = wr * 64 + (lane & 15);
  const int wcbase = wc * 32 + (lane & 15);
  const int a_off0 = (wrbase << 7) + (hi4 ^ xorv);
  const int a_off1 = (wrbase << 7) + ((64 | hi4) ^ xorv);
  const int b_off0 = 65536 + (wcbase << 7) + (hi4 ^ xorv);
  const int b_off1 = 65536 + (wcbase << 7) + ((64 | hi4) ^ xorv);
  const int wslot = (tid >> 6) << 10;
  const int s_lr0 = tid >> 3, s_lr1 = 64 + (tid >> 3);
  const int s_off0 = s_lr0 * K_DIM + (((tid & 7) ^ (s_lr0 & 7)) << 3);
  const int s_off1 = s_lr1 * K_DIM + (((tid & 7) ^ (s_lr1 & 7)) << 3);

  short8 a_[4][2], b_[2][2];
  f32x4 acc[2][2][4][2];
#pragma unroll
  for (int i = 0; i < 2; ++i)
#pragma unroll
    for (int j = 0; j < 2; ++j)
#pragma unroll
      for (int mf = 0; mf < 4; ++mf)
#pragma unroll
        for (int nf = 0; nf < 2; ++nf) acc[i][j][mf][nf] = (f32x4){0.f, 0.f, 0.f, 0.f};

  // prologue: buf0 <- kt0 (B00,A00,B01,A01), buf1 A10 <- kt1.
  // vmcnt(2): ALL buf0 loads landed (A10 pair still in flight); then a
  // barrier makes every wave's slots visible BEFORE any cross-slot ds_read.
  STG_B(0, 0, 0); STG_A(0, 0, 0); STG_B(0, 1, 0); STG_A(0, 1, 0);
  STG_A(1, 0, 1);
  VMCNT2;
  __builtin_amdgcn_s_barrier();
  LA(0, 0, 0); LB(0, 0, 0); LA(0, 0, 1); LB(0, 0, 1);  // reads for region 1

  for (int t = 0; t < 31; ++t) {
    const int kt1 = 2 * t + 1;     // buf0 = kt1-1, buf1 = kt1
    REGION(0, 0, LB(0,1,0),            LB(0,1,1),            STG_B(1,0,kt1),   VMCNT2);
    REGION(0, 1, LA(0,1,0),            LA(0,1,1),            STG_B(1,1,kt1),   VMCNT2);
    REGION(1, 1, LB(0,0,0),            LB(0,0,1),            STG_A(1,1,kt1),   VMCNT2);
    REGION(1, 0, LA(1,0,0); LB(1,0,0), LA(1,0,1); LB(1,0,1), STG_B(0,0,kt1+1), VMCNT2);
    REGION(0, 0, LB(1,1,0),            LB(1,1,1),            STG_A(0,0,kt1+1), VMCNT2);
    REGION(0, 1, LA(1,1,0),            LA(1,1,1),            STG_B(0,1,kt1+1), VMCNT2);
    REGION(1, 1, LB(1,0,0),            LB(1,0,1),            STG_A(0,1,kt1+1), VMCNT2);
    REGION(1, 0, LA(0,0,0); LB(0,0,0), LA(0,0,1); LB(0,0,1), STG_A(1,0,kt1+2), VMCNT2);
  }
  // peeled final iteration: buf0 = 62, buf1 = 63; no OOB stages, no next reads.
  // Drain of A11(63) pulled to p5 (vmcnt(0)) so p6's read is barrier-separated.
  REGION(0, 0, LB(0,1,0),            LB(0,1,1),            STG_B(1,0,63), VMCNT2);
  REGION(0, 1, LA(0,1,0),            LA(0,1,1),            STG_B(1,1,63), VMCNT2);
  REGION(1, 1, LB(0,0,0),            LB(0,0,1),            STG_A(1,1,63), VMCNT2);
  REGION(1, 0, LA(1,0,0); LB(1,0,0), LA(1,0,1); LB(1,0,1), NOOP,          VMCNT2);
  REGION(0, 0, LB(1,1,0),            LB(1,1,1),            NOOP,          VMCNT0);
  REGION(0, 1, LA(1,1,0),            LA(1,1,1),            NOOP,          NOOP);
  REGION(1, 1, LB(1,0,0),            LB(1,0,1),            NOOP,          NOOP);
  REGION(1, 0, NOOP,                 NOOP,                 NOOP,          NOOP);

  // epilogue: C/D layout col=lane&15, row=(lane>>4)*4+j
#pragma unroll
  for (int qn = 0; qn < 2; ++qn)
#pragma unroll
    for (int nf = 0; nf < 2; ++nf) {
      int gcol = n0 + qn * 128 + wc * 32 + nf * 16 + (lane & 15);
      float bv = bias[gcol];
#pragma unroll
      for (int qm = 0; qm < 2; ++qm)
#pragma unroll
        for (int mf = 0; mf < 4; ++mf) {
          int grow = m0 + qm * 128 + wr * 64 + mf * 16 + ((lane >> 4) << 2);
          f32x4 v = acc[qm][qn][mf][nf];
#pragma unroll
          for (int j = 0; j < 4; ++j)
            C[(size_t)(grow + j) * N_DIM + gcol] = v[j] + bv;
        }
    }
}

extern "C" void kernel_launch(void* const* d_in, const int* in_sizes, int n_in,
                              void* d_out, int out_size, void* d_ws, size_t ws_size,
                              hipStream_t stream) {
  const float* x       = (const float*)d_in[0];
  const int*   qweight = (const int*)d_in[1];
  const float* scale   = (const float*)d_in[2];
  const float* zero    = (const float*)d_in[3];
  const float* bias    = (const float*)d_in[4];
  float* out = (float*)d_out;

  unsigned short* Xb = (unsigned short*)d_ws;                    // 64 MB
  unsigned short* Wb = Xb + (size_t)M_DIM * K_DIM;               // 32 MB

  cast_x_kernel<<<(M_DIM * K_DIM / 8) / 256, 256, 0, stream>>>(x, Xb);
  dequant_kernel<<<(N_DIM * 128) / 256, 256, 0, stream>>>(qweight, scale, zero, Wb);
  gemm_kernel<<<(M_DIM / BM) * (N_DIM / BN), 512, 0, stream>>>(Xb, Wb, bias, out);
}